// Round 2
// baseline (112.610 us; speedup 1.0000x reference)
//
#include <hip/hip_runtime.h>
#include <hip/hip_bf16.h>

// Problem shape (fixed by setup_inputs): B=8, T=2048, C=1024, fp32.
// y[b,t,d] = v[b,1,d] where v = x @ W^T + bias  -> only t=1 rows of the GEMM
// matter. Single fused kernel. 256 blocks; block = (b, 32-wide d-chunk).
// Phase 1: 32 dot-products (len 1024) into LDS (~1-2 us, mostly L2-resident W).
// Phase 2: broadcast those 32 floats across all 2048 t-rows.
// R4/R5: phase-2 stores are NON-TEMPORAL (64 MiB stream > 32 MiB aggregate L2;
// write-allocate thrash buys nothing — bytes must reach HBM regardless).
// R5 fix: __builtin_nontemporal_store needs a clang ext_vector_type, not
// HIP's float4 struct.

#define B_  8
#define T_  2048
#define C_  1024

typedef float f4_t __attribute__((ext_vector_type(4)));

__global__ __launch_bounds__(256) void fused_target_attn(
    const float* __restrict__ x, const float* __restrict__ W,
    const float* __restrict__ bias, float* __restrict__ out) {
    __shared__ float v_s[32];

    const int bid = blockIdx.x;          // 0..255
    const int b   = bid >> 5;            // 8 batches
    const int d0  = (bid & 31) << 5;     // 32-float d-chunk
    // XCD note: blocks sharing a W-chunk are bid, bid+32, ... -> same XCD
    // under round-robin (32 % 8 == 0), so each XCD caches only 4 chunks
    // (512 KB) of W in its private L2.

    const int tid = threadIdx.x;         // 0..255
    const int row = tid >> 3;            // 0..31  (which d within chunk)
    const int sub = tid & 7;             // 8 threads per row

    // ---- Phase 1: v_s[row] = dot(x[b,1,:], W[d0+row,:]) + bias ----
    const float4* __restrict__ xr = reinterpret_cast<const float4*>(
        x + (size_t)b * T_ * C_ + C_);                 // t = 1
    const float4* __restrict__ wr = reinterpret_cast<const float4*>(
        W + (size_t)(d0 + row) * C_);

    float s = 0.f;
    // 256 float4 per row / 8 subs = 32 float4 per thread
    #pragma unroll
    for (int i = 0; i < 32; ++i) {
        const int k = sub + (i << 3);
        float4 a = xr[k];
        float4 w = wr[k];
        s += a.x * w.x + a.y * w.y + a.z * w.z + a.w * w.w;
    }
    // reduce the 8 sub-partials (lanes sub=0..7 are adjacent within a wave)
    s += __shfl_xor(s, 1, 64);
    s += __shfl_xor(s, 2, 64);
    s += __shfl_xor(s, 4, 64);
    if (sub == 0) v_s[row] = s + bias[d0 + row];
    __syncthreads();

    // ---- Phase 2: broadcast v_s[0..31] to all T rows ----
    // thread: t_sub = tid>>3 (0..31), d4 = tid&7 (8 float4 = 32 floats)
    const int t_sub = tid >> 3;
    const int d4    = tid & 7;
    const f4_t val = reinterpret_cast<const f4_t*>(v_s)[d4];

    // out as float4: index = (b*T + t)*256 + d0/4 + d4 ; t = t_sub + 32*k
    // 8 lanes x float4 = 128 B contiguous per t-row: full-line stores.
    f4_t* __restrict__ out4 = reinterpret_cast<f4_t*>(out);
    size_t idx = ((size_t)b << 19) + ((size_t)t_sub << 8) + (d0 >> 2) + d4;
    #pragma unroll 8
    for (int k = 0; k < 64; ++k) {       // t advances by 32 -> idx += 32*256
        __builtin_nontemporal_store(val, &out4[idx]);
        idx += 8192;
    }
}

extern "C" void kernel_launch(void* const* d_in, const int* in_sizes, int n_in,
                              void* d_out, int out_size, void* d_ws, size_t ws_size,
                              hipStream_t stream) {
    const float* x    = (const float*)d_in[0];
    const float* W    = (const float*)d_in[1];
    const float* bias = (const float*)d_in[2];
    float* out = (float*)d_out;

    fused_target_attn<<<256, 256, 0, stream>>>(x, W, bias, out);
}

// Round 3
// 109.370 us; speedup vs baseline: 1.0296x; 1.0296x over previous
//
#include <hip/hip_runtime.h>
#include <hip/hip_bf16.h>

// Problem shape (fixed by setup_inputs): B=8, T=2048, C=1024, fp32.
// y[b,t,d] = v[b,1,d] where v = x @ W^T + bias  -> only t=1 rows of the GEMM
// matter. R3: single fused kernel. 256 blocks; block = (b, 32-wide d-chunk).
// Phase 1: 32 dot-products (len 1024) into LDS. Phase 2: broadcast those 32
// floats across all 2048 t-rows (128B-contiguous float4 store groups).
// R6: REVERTED R5's non-temporal stores — measured +2.6us vs cached stores.
// L2 write-back absorbs the store burst (fill kernel proves 6.6 TB/s with
// cached stores); nt path gained nothing and cost ~2-3us. Keep cached.

#define B_  8
#define T_  2048
#define C_  1024

__global__ __launch_bounds__(256) void fused_target_attn(
    const float* __restrict__ x, const float* __restrict__ W,
    const float* __restrict__ bias, float* __restrict__ out) {
    __shared__ float v_s[32];

    const int bid = blockIdx.x;          // 0..255
    const int b   = bid >> 5;            // 8 batches
    const int d0  = (bid & 31) << 5;     // 32-float d-chunk
    // XCD note: blocks sharing a W-chunk are bid, bid+32, ... -> same XCD
    // under round-robin (32 % 8 == 0), so each XCD caches only 4 chunks
    // (512 KB) of W in its private L2.

    const int tid = threadIdx.x;         // 0..255
    const int row = tid >> 3;            // 0..31  (which d within chunk)
    const int sub = tid & 7;             // 8 threads per row

    // ---- Phase 1: v_s[row] = dot(x[b,1,:], W[d0+row,:]) + bias ----
    const float4* __restrict__ xr = reinterpret_cast<const float4*>(
        x + (size_t)b * T_ * C_ + C_);                 // t = 1
    const float4* __restrict__ wr = reinterpret_cast<const float4*>(
        W + (size_t)(d0 + row) * C_);

    float s = 0.f;
    // 256 float4 per row / 8 subs = 32 float4 per thread
    #pragma unroll
    for (int i = 0; i < 32; ++i) {
        const int k = sub + (i << 3);
        float4 a = xr[k];
        float4 w = wr[k];
        s += a.x * w.x + a.y * w.y + a.z * w.z + a.w * w.w;
    }
    // reduce the 8 sub-partials (lanes sub=0..7 are adjacent within a wave)
    s += __shfl_xor(s, 1, 64);
    s += __shfl_xor(s, 2, 64);
    s += __shfl_xor(s, 4, 64);
    if (sub == 0) v_s[row] = s + bias[d0 + row];
    __syncthreads();

    // ---- Phase 2: broadcast v_s[0..31] to all T rows ----
    // thread: t_sub = tid>>3 (0..31), d4 = tid&7 (8 float4 = 32 floats)
    const int t_sub = tid >> 3;
    const int d4    = tid & 7;
    const float4 val = reinterpret_cast<const float4*>(v_s)[d4];

    // out as float4: index = (b*T + t)*256 + d0/4 + d4 ; t = t_sub + 32*k
    // 8 lanes x float4 = 128 B contiguous per t-row: full-line stores.
    float4* __restrict__ out4 = reinterpret_cast<float4*>(out);
    size_t idx = ((size_t)b << 19) + ((size_t)t_sub << 8) + (d0 >> 2) + d4;
    #pragma unroll 8
    for (int k = 0; k < 64; ++k) {       // t advances by 32 -> idx += 32*256
        out4[idx] = val;
        idx += 8192;
    }
}

extern "C" void kernel_launch(void* const* d_in, const int* in_sizes, int n_in,
                              void* d_out, int out_size, void* d_ws, size_t ws_size,
                              hipStream_t stream) {
    const float* x    = (const float*)d_in[0];
    const float* W    = (const float*)d_in[1];
    const float* bias = (const float*)d_in[2];
    float* out = (float*)d_out;

    fused_target_attn<<<256, 256, 0, stream>>>(x, W, bias, out);
}